// Round 10
// baseline (177.373 us; speedup 1.0000x reference)
//
#include <hip/hip_runtime.h>
#include <hip/hip_bf16.h>
#include <cstddef>
#include <cstdint>

#define D_MODEL   256
#define N_HEADS   8
#define N_LEVELS  4
#define N_POINTS  4
#define D_HEAD    32
#define HLP       128      // N_HEADS*N_LEVELS*N_POINTS
#define NBATCH    4
#define LQ        4096
#define S_LEN     7680     // 4096+2048+1024+512
#define QB        2        // queries per sample block

typedef __attribute__((ext_vector_type(8))) short  short8;
typedef __attribute__((ext_vector_type(4))) float  f32x4;
typedef __attribute__((ext_vector_type(8))) unsigned short ushort8;

__device__ __forceinline__ unsigned short f2bf(float x) {
    __hip_bfloat16 h = __float2bfloat16(x);
    return *reinterpret_cast<unsigned short*>(&h);
}
__device__ __forceinline__ float bf2f(unsigned short u) {
    unsigned int v = ((unsigned int)u) << 16;
    return *reinterpret_cast<float*>(&v);
}

__device__ __forceinline__ void gload_lds16(const void* g, void* l) {
    __builtin_amdgcn_global_load_lds(
        (const __attribute__((address_space(1))) void*)g,
        (__attribute__((address_space(3))) void*)l,
        16, 0, 0);
}

// ---------------------------------------------------------------------------
// fp32 -> bf16 conversion for inflat (n_val elems) then query (n_q elems).
// Grid-stride, 8 elems/thread. Memory-bound (~72 MB => ~11 us).
// ---------------------------------------------------------------------------
__global__ __launch_bounds__(256) void conv_kernel(
    const float* __restrict__ inflat, const float* __restrict__ query,
    unsigned short* __restrict__ inflat_bf, unsigned short* __restrict__ query_bf,
    int n_val, int n_tot)
{
    size_t i = ((size_t)blockIdx.x * blockDim.x + threadIdx.x) * 8;
    if (i >= (size_t)n_tot) return;
    const float* src; unsigned short* dst; size_t off;
    if (i < (size_t)n_val) { src = inflat; dst = inflat_bf; off = i; }
    else                   { src = query;  dst = query_bf;  off = i - n_val; }
    float4 a = *(const float4*)(src + off);
    float4 b = *(const float4*)(src + off + 4);
    ushort8 r;
    r[0] = f2bf(a.x); r[1] = f2bf(a.y); r[2] = f2bf(a.z); r[3] = f2bf(a.w);
    r[4] = f2bf(b.x); r[5] = f2bf(b.y); r[6] = f2bf(b.z); r[7] = f2bf(b.w);
    *(ushort8*)(dst + off) = r;
}

// ---------------------------------------------------------------------------
// Fused weight prep: transpose [K=256][N] fp32 -> [N][K=256] bf16 for
// W_v (z=0), [W_off|W_aw] concat (z=1), W_out (z=2). Block (0,0,1) also
// writes bcat = [b_off|b_aw]. Grid (4,4,3), 256 threads.
// ---------------------------------------------------------------------------
__global__ __launch_bounds__(256) void prep_kernel(
    const float* __restrict__ W_v,  const float* __restrict__ W_off,
    const float* __restrict__ W_aw, const float* __restrict__ W_out,
    const float* __restrict__ b_off, const float* __restrict__ b_aw,
    unsigned short* __restrict__ Wv_t, unsigned short* __restrict__ Wcat_t,
    unsigned short* __restrict__ Wout_t, float* __restrict__ bcat)
{
    __shared__ float t[64][65];
    const int z   = blockIdx.z;
    const int k0  = blockIdx.y * 64;
    const int n0  = blockIdx.x * 64;
    const int tid = threadIdx.x;

    const float* src; int srcN; int cs; unsigned short* dst;
    if (z == 0)      { src = W_v;   srcN = 256; cs = n0;       dst = Wv_t;  }
    else if (z == 2) { src = W_out; srcN = 256; cs = n0;       dst = Wout_t;}
    else if (n0 < 128){ src = W_off; srcN = 128; cs = n0;      dst = Wcat_t;}
    else             { src = W_aw;  srcN = 128; cs = n0 - 128; dst = Wcat_t;}

    #pragma unroll
    for (int i = 0; i < 16; ++i) {
        int idx = tid + i * 256;
        int kk = idx >> 6, nn = idx & 63;
        t[kk][nn] = src[(size_t)(k0 + kk) * srcN + cs + nn];
    }
    __syncthreads();
    #pragma unroll
    for (int i = 0; i < 16; ++i) {
        int idx = tid + i * 256;
        int nn = idx >> 6, kk = idx & 63;
        dst[(size_t)(n0 + nn) * 256 + k0 + kk] = f2bf(t[kk][nn]);
    }
    if (z == 1 && blockIdx.x == 0 && blockIdx.y == 0) {
        bcat[tid] = (tid < 128) ? b_off[tid] : b_aw[tid - 128];
    }
}

// ---------------------------------------------------------------------------
// All-DMA bf16 MFMA GEMM (R3/R4-proven shape): 128x128 tile, 256 thr = 4
// waves (2x2), 16x16x32 MFMA, BK=32, single-buffered LDS, 2 barriers/K-step.
// Both A (row-major bf16) and B (N-major bf16) staged via global_load_lds
// width 16 -- deep HW DMA queue, no VGPR round-trip, no compiler
// serialization (R8/R9 showed VGPR-resident loads serialize per-load).
// Fused job space: job < njv -> value tile (bf16 out, [n][m][s][32] scatter),
// else P tile (fp32 out).
// ---------------------------------------------------------------------------
__global__ __launch_bounds__(256) void gemm_vp_kernel(
    const unsigned short* __restrict__ Abf_val,
    const unsigned short* __restrict__ Abf_qry,
    const unsigned short* __restrict__ Wv_t,
    const unsigned short* __restrict__ Wcat_t,
    const float* __restrict__ b_v, const float* __restrict__ bcat,
    unsigned short* __restrict__ value3, float* __restrict__ P)
{
    __shared__ alignas(16) unsigned short Als[8][64][8];   // 8 KiB
    __shared__ alignas(16) unsigned short Bls[8][64][8];   // 8 KiB

    const int job = blockIdx.x;
    const bool is_val = (job < 480);
    const int jj   = is_val ? job : (job - 480);
    const int row0 = (jj >> 1) * 128;
    const int col0 = (jj & 1) * 128;
    const unsigned short* A  = is_val ? Abf_val : Abf_qry;
    const unsigned short* Bt = is_val ? Wv_t : Wcat_t;
    const float* bias = is_val ? b_v : bcat;

    const int tid  = threadIdx.x;
    const int lane = tid & 63;
    const int w    = tid >> 6;
    const int wm   = w & 1;
    const int wn   = w >> 1;
    const int lr   = lane & 15;
    const int lk   = (lane >> 4) * 8;

    f32x4 acc[4][4] = {};

    for (int kt = 0; kt < 8; ++kt) {
        const int k0 = kt * 32;
        #pragma unroll
        for (int c = 0; c < 2; ++c) {
            const int im = w * 2 + c;
            gload_lds16(A  + (size_t)(row0 + im * 16 + lr) * 256 + k0 + lk, &Als[im][0][0]);
            gload_lds16(Bt + (size_t)(col0 + im * 16 + lr) * 256 + k0 + lk, &Bls[im][0][0]);
        }
        __syncthreads();

        short8 af[4], bfr[4];
        #pragma unroll
        for (int i = 0; i < 4; ++i) af[i]  = *(const short8*)&Als[wm * 4 + i][lane][0];
        #pragma unroll
        for (int j = 0; j < 4; ++j) bfr[j] = *(const short8*)&Bls[wn * 4 + j][lane][0];

        #pragma unroll
        for (int i = 0; i < 4; ++i)
            #pragma unroll
            for (int j = 0; j < 4; ++j)
                acc[i][j] = __builtin_amdgcn_mfma_f32_16x16x32_bf16(
                    af[i], bfr[j], acc[i][j], 0, 0, 0);
        __syncthreads();
    }

    const int prow = (lane >> 4) * 4;
    const int pcol = lane & 15;
    if (is_val) {
        const int n  = row0 / S_LEN;           // 7680 = 60*128: no straddle
        const int s0 = row0 - n * S_LEN + wm * 64;
        #pragma unroll
        for (int j = 0; j < 4; ++j) {
            const int col = col0 + wn * 64 + j * 16 + pcol;
            const float bs = bias[col];
            const int m = col >> 5, d = col & 31;
            unsigned short* dst = value3 + ((size_t)(n * 8 + m) * S_LEN + s0) * 32 + d;
            #pragma unroll
            for (int i = 0; i < 4; ++i)
                #pragma unroll
                for (int r = 0; r < 4; ++r)
                    dst[(size_t)(i * 16 + prow + r) * 32] = f2bf(acc[i][j][r] + bs);
        }
    } else {
        #pragma unroll
        for (int j = 0; j < 4; ++j) {
            const int col = col0 + wn * 64 + j * 16 + pcol;
            const float bs = bias[col];
            #pragma unroll
            for (int i = 0; i < 4; ++i)
                #pragma unroll
                for (int r = 0; r < 4; ++r)
                    P[(size_t)(row0 + wm * 64 + i * 16 + prow + r) * 256 + col]
                        = acc[i][j][r] + bs;
        }
    }
}

// ---------------------------------------------------------------------------
// Out-proj GEMM, same all-DMA shape: C[16384,256] = tbuf @ Wout_t^T + b_out.
// Grid 256 (all resident), fp32 out.
// ---------------------------------------------------------------------------
__global__ __launch_bounds__(256) void gemm_out_kernel(
    const unsigned short* __restrict__ A,
    const unsigned short* __restrict__ Bt,
    const float* __restrict__ bias,
    float* __restrict__ Cout)
{
    __shared__ alignas(16) unsigned short Als[8][64][8];
    __shared__ alignas(16) unsigned short Bls[8][64][8];

    const int jj   = blockIdx.x;
    const int row0 = (jj >> 1) * 128;
    const int col0 = (jj & 1) * 128;

    const int tid  = threadIdx.x;
    const int lane = tid & 63;
    const int w    = tid >> 6;
    const int wm   = w & 1;
    const int wn   = w >> 1;
    const int lr   = lane & 15;
    const int lk   = (lane >> 4) * 8;

    f32x4 acc[4][4] = {};

    for (int kt = 0; kt < 8; ++kt) {
        const int k0 = kt * 32;
        #pragma unroll
        for (int c = 0; c < 2; ++c) {
            const int im = w * 2 + c;
            gload_lds16(A  + (size_t)(row0 + im * 16 + lr) * 256 + k0 + lk, &Als[im][0][0]);
            gload_lds16(Bt + (size_t)(col0 + im * 16 + lr) * 256 + k0 + lk, &Bls[im][0][0]);
        }
        __syncthreads();

        short8 af[4], bfr[4];
        #pragma unroll
        for (int i = 0; i < 4; ++i) af[i]  = *(const short8*)&Als[wm * 4 + i][lane][0];
        #pragma unroll
        for (int j = 0; j < 4; ++j) bfr[j] = *(const short8*)&Bls[wn * 4 + j][lane][0];

        #pragma unroll
        for (int i = 0; i < 4; ++i)
            #pragma unroll
            for (int j = 0; j < 4; ++j)
                acc[i][j] = __builtin_amdgcn_mfma_f32_16x16x32_bf16(
                    af[i], bfr[j], acc[i][j], 0, 0, 0);
        __syncthreads();
    }

    const int prow = (lane >> 4) * 4;
    const int pcol = lane & 15;
    #pragma unroll
    for (int j = 0; j < 4; ++j) {
        const int col = col0 + wn * 64 + j * 16 + pcol;
        const float bs = bias[col];
        #pragma unroll
        for (int i = 0; i < 4; ++i)
            #pragma unroll
            for (int r = 0; r < 4; ++r)
                Cout[(size_t)(row0 + wm * 64 + i * 16 + prow + r) * 256 + col]
                    = acc[i][j][r] + bs;
    }
}

// ---------------------------------------------------------------------------
// Sampling + softmax, TLP-oriented. 8192 blocks x 256 thr, QB=2.
// Thread map: tid = q*128 + m*16 + ql*4 + c
//   q = query (0..1), m = head, ql = 8-dim group, c = LEVEL (0..3).
// Each thread: the 4 samples of its level -> ONE round of 8 independent
// 16 B gathers (R7-R9's 4 serialized rounds were the latency sink), then
// 2-step shfl_xor (1,2) sums over levels. blockIdx&7 keeps batch n's
// 3.93 MB value slice in the two XCDs serving it.
// ---------------------------------------------------------------------------
__global__ __launch_bounds__(256) void sample_kernel(
    const float* __restrict__ P, const float* __restrict__ refp,
    const int* __restrict__ shapes, const int* __restrict__ lstart,
    const unsigned short* __restrict__ value3,
    unsigned short* __restrict__ tout)
{
    __shared__ int   sG0[QB][130];
    __shared__ float sW [QB][130];
    __shared__ float sA [QB][130];
    __shared__ int   glim[4];

    const int b    = blockIdx.x;       // 0..8191
    const int xcd  = b & 7;
    const int n    = xcd >> 1;
    const int half = xcd & 1;
    const int slot = b >> 3;           // 0..1023
    const int q0   = (slot * 2 + half) * QB;
    const int nq0  = n * LQ + q0;
    const int tid  = threadIdx.x;

    if (tid < 4) glim[tid] = lstart[tid] + shapes[tid] - 1;

    // phase 1: one item per thread (2 queries x 128 points)
    {
        const int q  = tid >> 7;
        const int j  = tid & 127;         // m*16 + l*4 + p
        const int l  = (j >> 2) & 3;
        const int nq = nq0 + q;
        const float off   = __builtin_nontemporal_load(P + (size_t)nq * 256 + j);
        const float logit = __builtin_nontemporal_load(P + (size_t)nq * 256 + 128 + j);
        const float ref   = __builtin_nontemporal_load(refp + (size_t)nq * N_LEVELS + l);
        const int   sh    = shapes[l];
        const float Tf    = (float)sh;
        float x = ref * Tf + off - 0.5f;
        x = fminf(fmaxf(x, 0.0f), Tf - 1.0f);
        const float x0 = floorf(x);
        sG0[q][j] = (int)x0 + lstart[l];
        sW [q][j] = x - x0;
        sA [q][j] = logit;
    }
    __syncthreads();

    // phase 2: per-thread 4 samples (level c), 8 gathers in one round
    const int q  = tid >> 7;
    const int m  = (tid >> 4) & 7;
    const int ql = (tid >> 2) & 3;
    const int c  = tid & 3;            // level
    const unsigned short* vb =
        value3 + (size_t)(n * 8 + m) * S_LEN * 32 + ql * 8;

    // softmax over all 16 points of (q,m), in-register (redundant x16 lanes)
    float e[16];
    float mx = -1e30f;
    #pragma unroll
    for (int i = 0; i < 16; ++i) { e[i] = sA[q][m * 16 + i]; mx = fmaxf(mx, e[i]); }
    float s = 0.f;
    #pragma unroll
    for (int i = 0; i < 16; ++i) { e[i] = __expf(e[i] - mx); s += e[i]; }
    const float rs = 1.0f / s;

    // gather: 4 samples x 2 rows, all independent
    const int lim = glim[c];
    ushort8 u0[4], u1[4];
    float   cw[4];
    int     g0v[4];
    #pragma unroll
    for (int sIdx = 0; sIdx < 4; ++sIdx) {
        const int j = m * 16 + c * 4 + sIdx;
        cw[sIdx]  = sW[q][j];
        g0v[sIdx] = sG0[q][j];
    }
    #pragma unroll
    for (int sIdx = 0; sIdx < 4; ++sIdx) {
        const int g0 = g0v[sIdx];
        const int g1 = min(g0 + 1, lim);
        u0[sIdx] = *(const ushort8*)(vb + (size_t)g0 * 32);
        u1[sIdx] = *(const ushort8*)(vb + (size_t)g1 * 32);
    }

    float acc[8] = {};
    #pragma unroll
    for (int sIdx = 0; sIdx < 4; ++sIdx) {
        const float a  = e[c * 4 + sIdx] * rs;
        const float w1 = cw[sIdx];
        const float c0 = a * (1.0f - w1);
        const float c1 = a * w1;
        #pragma unroll
        for (int d = 0; d < 8; ++d)
            acc[d] += c0 * bf2f(u0[sIdx][d]) + c1 * bf2f(u1[sIdx][d]);
    }

    // reduce over levels: lanes c=0..3 (xor 1, then 2)
    #pragma unroll
    for (int d = 0; d < 8; ++d) {
        acc[d] += __shfl_xor(acc[d], 1);
        acc[d] += __shfl_xor(acc[d], 2);
    }
    if (c == 0) {
        ushort8 o;
        #pragma unroll
        for (int d = 0; d < 8; ++d) o[d] = f2bf(acc[d]);
        __builtin_nontemporal_store(o,
            (ushort8*)(tout + (size_t)(nq0 + q) * 256 + m * 32 + ql * 8));
    }
}

// ---------------------------------------------------------------------------
extern "C" void kernel_launch(void* const* d_in, const int* in_sizes, int n_in,
                              void* d_out, int out_size, void* d_ws, size_t ws_size,
                              hipStream_t stream)
{
    const float* query  = (const float*)d_in[0];
    const float* refp   = (const float*)d_in[1];
    const float* inflat = (const float*)d_in[2];
    const int*   shapes = (const int*)d_in[3];
    const int*   lstart = (const int*)d_in[4];
    const float* W_off  = (const float*)d_in[5];
    const float* b_off  = (const float*)d_in[6];
    const float* W_aw   = (const float*)d_in[7];
    const float* b_aw   = (const float*)d_in[8];
    const float* W_v    = (const float*)d_in[9];
    const float* b_v    = (const float*)d_in[10];
    const float* W_out  = (const float*)d_in[11];
    const float* b_out  = (const float*)d_in[12];

    const int M_val = NBATCH * S_LEN;    // 30720
    const int M_q   = NBATCH * LQ;       // 16384
    const int n_val = M_val * D_MODEL;   // 7,864,320
    const int n_q   = M_q * D_MODEL;     // 4,194,304
    const int n_tot = n_val + n_q;

    // ---- workspace layout ----
    char* p = (char*)d_ws;
    unsigned short* value3    = (unsigned short*)p; p += (size_t)n_val * 2;   // 15.7 MB
    float*          P         = (float*)p;          p += (size_t)M_q * 256 * 4; // 16.8 MB
    unsigned short* tbuf      = (unsigned short*)p; p += (size_t)n_q * 2;     // 8.4 MB
    unsigned short* inflat_bf = (unsigned short*)p; p += (size_t)n_val * 2;   // 15.7 MB
    unsigned short* query_bf  = (unsigned short*)p; p += (size_t)n_q * 2;     // 8.4 MB
    unsigned short* Wv_t      = (unsigned short*)p; p += 256 * 256 * 2;
    unsigned short* Wcat_t    = (unsigned short*)p; p += 256 * 256 * 2;
    unsigned short* Wout_t    = (unsigned short*)p; p += 256 * 256 * 2;
    float*          bcat      = (float*)p;          p += 256 * 4;

    // 1. fp32 -> bf16 activations
    conv_kernel<<<(n_tot / 8 + 255) / 256, 256, 0, stream>>>(
        inflat, query, inflat_bf, query_bf, n_val, n_tot);
    // 2. weight prep
    prep_kernel<<<dim3(4, 4, 3), 256, 0, stream>>>(
        W_v, W_off, W_aw, W_out, b_off, b_aw, Wv_t, Wcat_t, Wout_t, bcat);
    // 3. value-GEMM (480 jobs) + P-GEMM (256 jobs), all-DMA staging
    gemm_vp_kernel<<<736, 256, 0, stream>>>(
        inflat_bf, query_bf, Wv_t, Wcat_t, b_v, bcat, value3, P);
    // 4. sampling + softmax -> tbuf (bf16)
    sample_kernel<<<8192, 256, 0, stream>>>(
        P, refp, shapes, lstart, value3, tbuf);
    // 5. out = tbuf @ W_out + b_out (all-DMA)
    gemm_out_kernel<<<256, 256, 0, stream>>>(
        tbuf, Wout_t, b_out, (float*)d_out);
}